// Round 1
// baseline (876.411 us; speedup 1.0000x reference)
//
#include <hip/hip_runtime.h>
#include <cstdint>
#include <cstddef>

// Problem constants
#define MM 8192      // batch
#define KK 4096      // in_dim
#define NN 2048      // out_dim
#define DEPTH_N 9

typedef __attribute__((ext_vector_type(8))) short bf16x8;    // 8 bf16 = 4 VGPRs
typedef __attribute__((ext_vector_type(16))) float f32x16;   // MFMA 32x32 accumulator

static_assert(sizeof(bf16x8) == 16, "bf16x8 must be 16B");
static_assert(sizeof(f32x16) == 64, "f32x16 must be 64B");

typedef const __attribute__((address_space(1))) uint32_t* gptr_t;
typedef __attribute__((address_space(3))) uint32_t* lptr_t;

__device__ __forceinline__ void load_lds16(const void* g, void* l) {
  // async global->LDS, 16B per lane; LDS dest is wave-uniform base + lane*16
  __builtin_amdgcn_global_load_lds((gptr_t)g, (lptr_t)l, 16, 0, 0);
}

union FragU {
  uint32_t u[4];
  bf16x8 v;
};

// Split a float4 into packed bf16 hi (truncate) and bf16 lo (truncate of residual).
__device__ __forceinline__ void split4(float4 v, uint32_t& h01, uint32_t& h23,
                                       uint32_t& l01, uint32_t& l23) {
  uint32_t ux = __float_as_uint(v.x), uy = __float_as_uint(v.y);
  uint32_t uz = __float_as_uint(v.z), uw = __float_as_uint(v.w);
  // D = src1.hi16 | src0.hi16<<16  (element order: low half first)
  h01 = __builtin_amdgcn_perm(uy, ux, 0x07060302u);
  h23 = __builtin_amdgcn_perm(uw, uz, 0x07060302u);
  float rx = v.x - __uint_as_float(ux & 0xFFFF0000u);
  float ry = v.y - __uint_as_float(uy & 0xFFFF0000u);
  float rz = v.z - __uint_as_float(uz & 0xFFFF0000u);
  float rw = v.w - __uint_as_float(uw & 0xFFFF0000u);
  l01 = __builtin_amdgcn_perm(__float_as_uint(ry), __float_as_uint(rx), 0x07060302u);
  l23 = __builtin_amdgcn_perm(__float_as_uint(rw), __float_as_uint(rz), 0x07060302u);
}

// ---------------------------------------------------------------------------
// Kernel 1: transpose + bf16-split classical_weights (K x N fp32, row-major)
// into BtHi/BtLo (N x K bf16, row-major).
// ---------------------------------------------------------------------------
__global__ __launch_bounds__(256) void prep_bt_kernel(
    const float* __restrict__ W,
    uint16_t* __restrict__ btHi,
    uint16_t* __restrict__ btLo) {
  __shared__ float tile[64][65];  // +1 pad breaks transpose-read conflicts
  const int k0 = blockIdx.x * 64;
  const int n0 = blockIdx.y * 64;
  const int c4 = (threadIdx.x & 15) * 4;
  const int r16 = threadIdx.x >> 4;  // 0..15
#pragma unroll
  for (int p = 0; p < 4; ++p) {
    int r = p * 16 + r16;
    float4 v = *(const float4*)(W + (size_t)(k0 + r) * NN + n0 + c4);
    tile[r][c4 + 0] = v.x;
    tile[r][c4 + 1] = v.y;
    tile[r][c4 + 2] = v.z;
    tile[r][c4 + 3] = v.w;
  }
  __syncthreads();
#pragma unroll
  for (int p = 0; p < 4; ++p) {
    int n = p * 16 + r16;
    ushort4 h, l;
    float f0 = tile[c4 + 0][n];
    float f1 = tile[c4 + 1][n];
    float f2 = tile[c4 + 2][n];
    float f3 = tile[c4 + 3][n];
    uint32_t u0 = __float_as_uint(f0), u1 = __float_as_uint(f1);
    uint32_t u2 = __float_as_uint(f2), u3 = __float_as_uint(f3);
    h.x = (uint16_t)(u0 >> 16);
    h.y = (uint16_t)(u1 >> 16);
    h.z = (uint16_t)(u2 >> 16);
    h.w = (uint16_t)(u3 >> 16);
    float r0 = f0 - __uint_as_float(u0 & 0xFFFF0000u);
    float r1 = f1 - __uint_as_float(u1 & 0xFFFF0000u);
    float r2 = f2 - __uint_as_float(u2 & 0xFFFF0000u);
    float r3 = f3 - __uint_as_float(u3 & 0xFFFF0000u);
    l.x = (uint16_t)(__float_as_uint(r0) >> 16);
    l.y = (uint16_t)(__float_as_uint(r1) >> 16);
    l.z = (uint16_t)(__float_as_uint(r2) >> 16);
    l.w = (uint16_t)(__float_as_uint(r3) >> 16);
    size_t off = (size_t)(n0 + n) * KK + k0 + c4;
    *(ushort4*)(btHi + off) = h;
    *(ushort4*)(btLo + off) = l;
  }
}

// ---------------------------------------------------------------------------
// Kernel 1b: split X (M x K fp32, row-major) into XHi/XLo bf16 (same layout).
// Removes the per-fragment split4 VALU work from the GEMM inner loop.
// ---------------------------------------------------------------------------
__global__ __launch_bounds__(256) void prep_x_kernel(
    const float* __restrict__ X,
    uint16_t* __restrict__ xHi,
    uint16_t* __restrict__ xLo) {
  size_t i = ((size_t)blockIdx.x * 256 + threadIdx.x) * 8;
  float4 v0 = *(const float4*)(X + i);
  float4 v1 = *(const float4*)(X + i + 4);
  uint32_t h01, h23, l01, l23, h45, h67, l45, l67;
  split4(v0, h01, h23, l01, l23);
  split4(v1, h45, h67, l45, l67);
  uint4 h, l;
  h.x = h01; h.y = h23; h.z = h45; h.w = h67;
  l.x = l01; l.y = l23; l.z = l45; l.w = l67;
  *(uint4*)(xHi + i) = h;
  *(uint4*)(xLo + i) = l;
}

// ---------------------------------------------------------------------------
// Kernel 2: bias2[j] = classical_biases[j] + (1/K) * prod_{d,c} cos^2(uw[d,j,c])
// (the scan on a constant state collapses to a cosine product)
// ---------------------------------------------------------------------------
__global__ __launch_bounds__(256) void prep_bias_kernel(
    const float* __restrict__ uw,
    const float* __restrict__ cb,
    float* __restrict__ bias2) {
  int j = blockIdx.x * 256 + threadIdx.x;  // grid covers exactly NN
  float p = 1.0f / (float)KK;
#pragma unroll
  for (int d = 0; d < DEPTH_N; ++d) {
    float4 v = *(const float4*)(uw + (size_t)d * KK * NN + (size_t)j * NN);
    float c0 = cosf(v.x), c1 = cosf(v.y), c2 = cosf(v.z);
    p *= (c0 * c0) * (c1 * c1) * (c2 * c2);
  }
  bias2[j] = cb[j] + p;
}

// ---------------------------------------------------------------------------
// Kernel 3 (new): all-bf16 GEMM  out = tanh(xHi/xLo @ btHi/btLo + bias2)
//   block tile 128x128, BK=32, 4 waves each 64x64 via 2x2 mfma_f32_32x32x16_bf16
//   All four operand arrays are [rows][K] bf16 row-major -> A staging/read path
//   is identical in structure to the (verified) B path.
//   Inner loop is pure ds_read_b128 -> MFMA: no split VALU on critical path.
// ---------------------------------------------------------------------------
__global__ __launch_bounds__(256, 4) void unl_gemm_ps_kernel(
    const uint16_t* __restrict__ XHi,
    const uint16_t* __restrict__ XLo,
    const uint16_t* __restrict__ BtHi,
    const uint16_t* __restrict__ BtLo,
    const float* __restrict__ bias2,
    float* __restrict__ Out) {
  __shared__ __align__(16) uint8_t smem[32768];
  char* sAh = (char*)smem;           // [128][32] bf16 hi, swizzled (8KB)
  char* sAl = (char*)smem + 8192;    // [128][32] bf16 lo
  char* sBh = (char*)smem + 16384;   // [128][32] bf16 hi
  char* sBl = (char*)smem + 24576;   // [128][32] bf16 lo

  const int tid = threadIdx.x;
  const int lane = tid & 63;
  const int wq = __builtin_amdgcn_readfirstlane(tid >> 6);
  const int wM = wq >> 1;
  const int wN = wq & 1;
  const int lane31 = lane & 31;
  const int kh = lane >> 5;  // k-half selector for MFMA operand layout

  const int bidx = blockIdx.x;
  const int m0 = (bidx & 63) * 128;  // 64 m-tiles
  const int n0 = (bidx >> 6) * 128;  // 16 n-tiles

  // ---- staging: 1KB chunks; chunk idx = wq*2+q covers rows idx*16+(lane>>2),
  //      physical 16B block p=lane&3 holds logical k-block c = p ^ ((row>>1)&3)
  const int bC = (lane & 3) ^ ((lane >> 3) & 3);
  const int bVoff = ((lane >> 2) * KK + bC * 8) * 2;  // bytes into row-block
  const char* aBaseH = (const char*)(XHi + (size_t)(m0 + wq * 32) * KK) + bVoff;
  const char* aBaseL = (const char*)(XLo + (size_t)(m0 + wq * 32) * KK) + bVoff;
  const char* bBaseH = (const char*)(BtHi + (size_t)(n0 + wq * 32) * KK) + bVoff;
  const char* bBaseL = (const char*)(BtLo + (size_t)(n0 + wq * 32) * KK) + bVoff;

  // ---- fragment read byte-offsets (swizzle-corrected) ----
  // read for (t,s): row = w*64+t*32+lane31, logical c = 2s+kh,
  //   byte addr = row*64 + (c^((row>>1)&3))*16
  int aOffB[2][2], bOffB[2][2];
#pragma unroll
  for (int mt = 0; mt < 2; ++mt) {
    int row = wM * 64 + mt * 32 + lane31;
#pragma unroll
    for (int s = 0; s < 2; ++s)
      aOffB[mt][s] = row * 64 + (((2 * s + kh) ^ ((row >> 1) & 3)) * 16);
  }
#pragma unroll
  for (int nt = 0; nt < 2; ++nt) {
    int row = wN * 64 + nt * 32 + lane31;
#pragma unroll
    for (int s = 0; s < 2; ++s)
      bOffB[nt][s] = row * 64 + (((2 * s + kh) ^ ((row >> 1) & 3)) * 16);
  }

  f32x16 acc[2][2];
#pragma unroll
  for (int mt = 0; mt < 2; ++mt)
#pragma unroll
    for (int nt = 0; nt < 2; ++nt)
#pragma unroll
      for (int r = 0; r < 16; ++r) acc[mt][nt][r] = 0.0f;

  for (int kt = 0; kt < KK; kt += 32) {
    __syncthreads();  // previous tile fully consumed
#pragma unroll
    for (int q = 0; q < 2; ++q) {
      load_lds16(aBaseH + (size_t)kt * 2 + (size_t)q * (16 * KK * 2),
                 sAh + (wq * 2 + q) * 1024);
      load_lds16(aBaseL + (size_t)kt * 2 + (size_t)q * (16 * KK * 2),
                 sAl + (wq * 2 + q) * 1024);
      load_lds16(bBaseH + (size_t)kt * 2 + (size_t)q * (16 * KK * 2),
                 sBh + (wq * 2 + q) * 1024);
      load_lds16(bBaseL + (size_t)kt * 2 + (size_t)q * (16 * KK * 2),
                 sBl + (wq * 2 + q) * 1024);
    }
    __syncthreads();  // drains vmcnt: staging complete

#pragma unroll
    for (int s = 0; s < 2; ++s) {
      bf16x8 ah[2], al[2], bh[2], bl[2];
#pragma unroll
      for (int mt = 0; mt < 2; ++mt) {
        ah[mt] = *(const bf16x8*)(sAh + aOffB[mt][s]);
        al[mt] = *(const bf16x8*)(sAl + aOffB[mt][s]);
      }
#pragma unroll
      for (int nt = 0; nt < 2; ++nt) {
        bh[nt] = *(const bf16x8*)(sBh + bOffB[nt][s]);
        bl[nt] = *(const bf16x8*)(sBl + bOffB[nt][s]);
      }
#pragma unroll
      for (int mt = 0; mt < 2; ++mt) {
#pragma unroll
        for (int nt = 0; nt < 2; ++nt) {
          acc[mt][nt] = __builtin_amdgcn_mfma_f32_32x32x16_bf16(ah[mt], bh[nt], acc[mt][nt], 0, 0, 0);
          acc[mt][nt] = __builtin_amdgcn_mfma_f32_32x32x16_bf16(ah[mt], bl[nt], acc[mt][nt], 0, 0, 0);
          acc[mt][nt] = __builtin_amdgcn_mfma_f32_32x32x16_bf16(al[mt], bh[nt], acc[mt][nt], 0, 0, 0);
        }
      }
    }
  }

  // ---- epilogue: out = tanh(acc + bias2) ----
  // C/D layout (verified m74/m101): col = lane&31, row = (r&3) + 8*(r>>2) + 4*kh
#pragma unroll
  for (int nt = 0; nt < 2; ++nt) {
    int col = n0 + wN * 64 + nt * 32 + lane31;
    float b2 = bias2[col];
#pragma unroll
    for (int mt = 0; mt < 2; ++mt) {
#pragma unroll
      for (int r = 0; r < 16; ++r) {
        int rowl = (r & 3) + 8 * (r >> 2) + 4 * kh;
        int grow = m0 + wM * 64 + mt * 32 + rowl;
        float z = acc[mt][nt][r] + b2;
        z = fminf(fmaxf(z, -12.0f), 12.0f);  // tanh saturated well before 12
        float t = __expf(2.0f * z);
        Out[(size_t)grow * NN + col] = (t - 1.0f) / (t + 1.0f);
      }
    }
  }
}

// ---------------------------------------------------------------------------
// Kernel 3 (fallback, measured 814us): on-the-fly split GEMM. Used only if the
// workspace is too small for the pre-split X arrays.
// ---------------------------------------------------------------------------
__global__ __launch_bounds__(256, 4) void unl_gemm_kernel(
    const float* __restrict__ X,
    const uint16_t* __restrict__ BtHi,
    const uint16_t* __restrict__ BtLo,
    const float* __restrict__ bias2,
    float* __restrict__ Out) {
  __shared__ __align__(16) uint8_t smem[32768];
  char* sA = (char*)smem;           // [128][32] fp32, 16B-swizzled (16KB)
  char* sBh = (char*)smem + 16384;  // [128][32] bf16 hi, swizzled (8KB)
  char* sBl = (char*)smem + 24576;  // [128][32] bf16 lo, swizzled (8KB)

  const int tid = threadIdx.x;
  const int lane = tid & 63;
  const int wq = __builtin_amdgcn_readfirstlane(tid >> 6);
  const int wM = wq >> 1;
  const int wN = wq & 1;
  const int lane31 = lane & 31;
  const int kh = lane >> 5;

  const int bidx = blockIdx.x;
  const int m0 = (bidx & 63) * 128;
  const int n0 = (bidx >> 6) * 128;

  const int aC = (lane & 7) ^ (lane >> 3);
  const int aVoff = ((lane >> 3) * KK + aC * 4) * 4;
  const char* aBase = (const char*)(X + (size_t)(m0 + wq * 32) * KK) + aVoff;
  const int bC = (lane & 3) ^ ((lane >> 3) & 3);
  const int bVoff = ((lane >> 2) * KK + bC * 8) * 2;
  const char* bBaseH = (const char*)(BtHi + (size_t)(n0 + wq * 32) * KK) + bVoff;
  const char* bBaseL = (const char*)(BtLo + (size_t)(n0 + wq * 32) * KK) + bVoff;

  int aOffB[2][2];
#pragma unroll
  for (int mt = 0; mt < 2; ++mt) {
    int row = wM * 64 + mt * 32 + lane31;
#pragma unroll
    for (int s = 0; s < 2; ++s)
      aOffB[mt][s] = row * 128 + (((4 * s + 2 * kh) ^ (row & 7)) * 16);
  }
  int bOffB[2][2];
#pragma unroll
  for (int nt = 0; nt < 2; ++nt) {
    int row = wN * 64 + nt * 32 + lane31;
#pragma unroll
    for (int s = 0; s < 2; ++s)
      bOffB[nt][s] = row * 64 + (((2 * s + kh) ^ ((row >> 1) & 3)) * 16);
  }

  f32x16 acc[2][2];
#pragma unroll
  for (int mt = 0; mt < 2; ++mt)
#pragma unroll
    for (int nt = 0; nt < 2; ++nt)
#pragma unroll
      for (int r = 0; r < 16; ++r) acc[mt][nt][r] = 0.0f;

  for (int kt = 0; kt < KK; kt += 32) {
    __syncthreads();
#pragma unroll
    for (int q = 0; q < 4; ++q)
      load_lds16(aBase + (size_t)kt * 4 + (size_t)q * (8 * KK * 4),
                 sA + (wq * 4 + q) * 1024);
#pragma unroll
    for (int q = 0; q < 2; ++q) {
      load_lds16(bBaseH + (size_t)kt * 2 + (size_t)q * (16 * KK * 2),
                 sBh + (wq * 2 + q) * 1024);
      load_lds16(bBaseL + (size_t)kt * 2 + (size_t)q * (16 * KK * 2),
                 sBl + (wq * 2 + q) * 1024);
    }
    __syncthreads();

#pragma unroll
    for (int s = 0; s < 2; ++s) {
      bf16x8 ah[2], al[2], bh[2], bl[2];
#pragma unroll
      for (int mt = 0; mt < 2; ++mt) {
        float4 v0 = *(const float4*)(sA + aOffB[mt][s]);
        float4 v1 = *(const float4*)(sA + (aOffB[mt][s] ^ 16));
        FragU uh, ul;
        split4(v0, uh.u[0], uh.u[1], ul.u[0], ul.u[1]);
        split4(v1, uh.u[2], uh.u[3], ul.u[2], ul.u[3]);
        ah[mt] = uh.v;
        al[mt] = ul.v;
      }
#pragma unroll
      for (int nt = 0; nt < 2; ++nt) {
        bh[nt] = *(const bf16x8*)(sBh + bOffB[nt][s]);
        bl[nt] = *(const bf16x8*)(sBl + bOffB[nt][s]);
      }
#pragma unroll
      for (int mt = 0; mt < 2; ++mt) {
#pragma unroll
        for (int nt = 0; nt < 2; ++nt) {
          acc[mt][nt] = __builtin_amdgcn_mfma_f32_32x32x16_bf16(ah[mt], bh[nt], acc[mt][nt], 0, 0, 0);
          acc[mt][nt] = __builtin_amdgcn_mfma_f32_32x32x16_bf16(ah[mt], bl[nt], acc[mt][nt], 0, 0, 0);
          acc[mt][nt] = __builtin_amdgcn_mfma_f32_32x32x16_bf16(al[mt], bh[nt], acc[mt][nt], 0, 0, 0);
        }
      }
    }
  }

#pragma unroll
  for (int nt = 0; nt < 2; ++nt) {
    int col = n0 + wN * 64 + nt * 32 + lane31;
    float b2 = bias2[col];
#pragma unroll
    for (int mt = 0; mt < 2; ++mt) {
#pragma unroll
      for (int r = 0; r < 16; ++r) {
        int rowl = (r & 3) + 8 * (r >> 2) + 4 * kh;
        int grow = m0 + wM * 64 + mt * 32 + rowl;
        float z = acc[mt][nt][r] + b2;
        z = fminf(fmaxf(z, -12.0f), 12.0f);
        float t = __expf(2.0f * z);
        Out[(size_t)grow * NN + col] = (t - 1.0f) / (t + 1.0f);
      }
    }
  }
}

// ---------------------------------------------------------------------------
extern "C" void kernel_launch(void* const* d_in, const int* in_sizes, int n_in,
                              void* d_out, int out_size, void* d_ws, size_t ws_size,
                              hipStream_t stream) {
  const float* x = (const float*)d_in[0];   // (8192, 4096)
  const float* uw = (const float*)d_in[1];  // (9, 4096, 2048)
  const float* cw = (const float*)d_in[2];  // (4096, 2048)
  const float* cb = (const float*)d_in[3];  // (2048,)
  float* out = (float*)d_out;               // (8192, 2048)

  // workspace layout: BtHi (16MB) | BtLo (16MB) | bias2 (8KB) | XHi (64MB) | XLo (64MB)
  uint16_t* btHi = (uint16_t*)d_ws;
  uint16_t* btLo = btHi + (size_t)NN * KK;
  float* bias2 = (float*)(btLo + (size_t)NN * KK);
  uint16_t* xHi = (uint16_t*)(bias2 + NN);
  uint16_t* xLo = xHi + (size_t)MM * KK;

  const size_t need = (size_t)NN * KK * 4   // BtHi+BtLo
                    + (size_t)NN * 4        // bias2
                    + (size_t)MM * KK * 4;  // XHi+XLo

  prep_bt_kernel<<<dim3(KK / 64, NN / 64), 256, 0, stream>>>(cw, btHi, btLo);
  prep_bias_kernel<<<dim3(NN / 256), 256, 0, stream>>>(uw, cb, bias2);

  if (ws_size >= need) {
    prep_x_kernel<<<dim3((MM * KK) / (256 * 8)), 256, 0, stream>>>(x, xHi, xLo);
    unl_gemm_ps_kernel<<<dim3((MM / 128) * (NN / 128)), 256, 0, stream>>>(
        xHi, xLo, btHi, btLo, bias2, out);
  } else {
    unl_gemm_kernel<<<dim3((MM / 128) * (NN / 128)), 256, 0, stream>>>(
        x, btHi, btLo, bias2, out);
  }
}

// Round 2
// 844.758 us; speedup vs baseline: 1.0375x; 1.0375x over previous
//
#include <hip/hip_runtime.h>
#include <cstdint>
#include <cstddef>

// Problem constants
#define MM 8192      // batch
#define KK 4096      // in_dim
#define NN 2048      // out_dim
#define DEPTH_N 9

typedef __attribute__((ext_vector_type(8))) short bf16x8;    // 8 bf16 = 4 VGPRs
typedef __attribute__((ext_vector_type(16))) float f32x16;   // MFMA 32x32 accumulator

static_assert(sizeof(bf16x8) == 16, "bf16x8 must be 16B");
static_assert(sizeof(f32x16) == 64, "f32x16 must be 64B");

typedef const __attribute__((address_space(1))) uint32_t* gptr_t;
typedef __attribute__((address_space(3))) uint32_t* lptr_t;

__device__ __forceinline__ void load_lds16(const void* g, void* l) {
  // async global->LDS, 16B per lane; LDS dest is wave-uniform base + lane*16
  __builtin_amdgcn_global_load_lds((gptr_t)g, (lptr_t)l, 16, 0, 0);
}

union FragU {
  uint32_t u[4];
  bf16x8 v;
};

// Split a float4 into packed bf16 hi (truncate) and bf16 lo (truncate of residual).
__device__ __forceinline__ void split4(float4 v, uint32_t& h01, uint32_t& h23,
                                       uint32_t& l01, uint32_t& l23) {
  uint32_t ux = __float_as_uint(v.x), uy = __float_as_uint(v.y);
  uint32_t uz = __float_as_uint(v.z), uw = __float_as_uint(v.w);
  h01 = __builtin_amdgcn_perm(uy, ux, 0x07060302u);
  h23 = __builtin_amdgcn_perm(uw, uz, 0x07060302u);
  float rx = v.x - __uint_as_float(ux & 0xFFFF0000u);
  float ry = v.y - __uint_as_float(uy & 0xFFFF0000u);
  float rz = v.z - __uint_as_float(uz & 0xFFFF0000u);
  float rw = v.w - __uint_as_float(uw & 0xFFFF0000u);
  l01 = __builtin_amdgcn_perm(__float_as_uint(ry), __float_as_uint(rx), 0x07060302u);
  l23 = __builtin_amdgcn_perm(__float_as_uint(rw), __float_as_uint(rz), 0x07060302u);
}

// ---------------------------------------------------------------------------
// Kernel 1: transpose + bf16-split classical_weights (K x N fp32, row-major)
// into BtHi/BtLo (N x K bf16, row-major).
// ---------------------------------------------------------------------------
__global__ __launch_bounds__(256) void prep_bt_kernel(
    const float* __restrict__ W,
    uint16_t* __restrict__ btHi,
    uint16_t* __restrict__ btLo) {
  __shared__ float tile[64][65];  // +1 pad breaks transpose-read conflicts
  const int k0 = blockIdx.x * 64;
  const int n0 = blockIdx.y * 64;
  const int c4 = (threadIdx.x & 15) * 4;
  const int r16 = threadIdx.x >> 4;  // 0..15
#pragma unroll
  for (int p = 0; p < 4; ++p) {
    int r = p * 16 + r16;
    float4 v = *(const float4*)(W + (size_t)(k0 + r) * NN + n0 + c4);
    tile[r][c4 + 0] = v.x;
    tile[r][c4 + 1] = v.y;
    tile[r][c4 + 2] = v.z;
    tile[r][c4 + 3] = v.w;
  }
  __syncthreads();
#pragma unroll
  for (int p = 0; p < 4; ++p) {
    int n = p * 16 + r16;
    ushort4 h, l;
    float f0 = tile[c4 + 0][n];
    float f1 = tile[c4 + 1][n];
    float f2 = tile[c4 + 2][n];
    float f3 = tile[c4 + 3][n];
    uint32_t u0 = __float_as_uint(f0), u1 = __float_as_uint(f1);
    uint32_t u2 = __float_as_uint(f2), u3 = __float_as_uint(f3);
    h.x = (uint16_t)(u0 >> 16);
    h.y = (uint16_t)(u1 >> 16);
    h.z = (uint16_t)(u2 >> 16);
    h.w = (uint16_t)(u3 >> 16);
    float r0 = f0 - __uint_as_float(u0 & 0xFFFF0000u);
    float r1 = f1 - __uint_as_float(u1 & 0xFFFF0000u);
    float r2 = f2 - __uint_as_float(u2 & 0xFFFF0000u);
    float r3 = f3 - __uint_as_float(u3 & 0xFFFF0000u);
    l.x = (uint16_t)(__float_as_uint(r0) >> 16);
    l.y = (uint16_t)(__float_as_uint(r1) >> 16);
    l.z = (uint16_t)(__float_as_uint(r2) >> 16);
    l.w = (uint16_t)(__float_as_uint(r3) >> 16);
    size_t off = (size_t)(n0 + n) * KK + k0 + c4;
    *(ushort4*)(btHi + off) = h;
    *(ushort4*)(btLo + off) = l;
  }
}

// ---------------------------------------------------------------------------
// Kernel 1b: split X (M x K fp32, row-major) into XHi/XLo bf16 (same layout).
// ---------------------------------------------------------------------------
__global__ __launch_bounds__(256) void prep_x_kernel(
    const float* __restrict__ X,
    uint16_t* __restrict__ xHi,
    uint16_t* __restrict__ xLo) {
  size_t i = ((size_t)blockIdx.x * 256 + threadIdx.x) * 8;
  float4 v0 = *(const float4*)(X + i);
  float4 v1 = *(const float4*)(X + i + 4);
  uint32_t h01, h23, l01, l23, h45, h67, l45, l67;
  split4(v0, h01, h23, l01, l23);
  split4(v1, h45, h67, l45, l67);
  uint4 h, l;
  h.x = h01; h.y = h23; h.z = h45; h.w = h67;
  l.x = l01; l.y = l23; l.z = l45; l.w = l67;
  *(uint4*)(xHi + i) = h;
  *(uint4*)(xLo + i) = l;
}

// ---------------------------------------------------------------------------
// Kernel 2: bias2[j] = classical_biases[j] + (1/K) * prod_{d,c} cos^2(uw[d,j,c])
// ---------------------------------------------------------------------------
__global__ __launch_bounds__(256) void prep_bias_kernel(
    const float* __restrict__ uw,
    const float* __restrict__ cb,
    float* __restrict__ bias2) {
  int j = blockIdx.x * 256 + threadIdx.x;  // grid covers exactly NN
  float p = 1.0f / (float)KK;
#pragma unroll
  for (int d = 0; d < DEPTH_N; ++d) {
    float4 v = *(const float4*)(uw + (size_t)d * KK * NN + (size_t)j * NN);
    float c0 = cosf(v.x), c1 = cosf(v.y), c2 = cosf(v.z);
    p *= (c0 * c0) * (c1 * c1) * (c2 * c2);
  }
  bias2[j] = cb[j] + p;
}

// ---------------------------------------------------------------------------
// Kernel 3: 256x256-tile bf16 GEMM with counted-vmcnt prefetch.
//   Grid 256 = 1 block/CU. 512 threads = 8 waves (2M x 4N), wave tile 128x64
//   (4x2 of 32x32 mfma). BK=64. LDS = 2 x (A 32KB + B 32KB) = 128KB dynamic,
//   double-buffered. Virtual K = 3 passes x 4096 over operand pairs
//   (XHi*BtHi, XHi*BtLo, XLo*BtHi) sharing one accumulator.
//   Each wave stages ONLY the slab rows it consumes (8 gload_lds/tile), so
//   `s_waitcnt vmcnt(8)` + raw s_barrier gives each tile's loads a full
//   tile (~2000 cy) of flight across the previous tile's MFMAs.
//   LDS rows are 128B with the ((l&7)^(l>>3)) 16B-block involution applied on
//   the GLOBAL source (linear LDS dest, Rule 21); fragment ds_read_b128s then
//   spread 8 lanes per 16B column = structural minimum (conflict-free).
// ---------------------------------------------------------------------------
__device__ __forceinline__ void stage_tile(
    int g, char* smembase,
    const char* pAh, const char* pAl, const char* pBh, const char* pBl,
    uint32_t aSrcOff, uint32_t bSrcOff, uint32_t aLdsOff, uint32_t bLdsOff) {
  const int pass = g >> 6;        // 0..2
  const int kt = g & 63;          // K-tile within pass
  const char* pA = (pass == 2) ? pAl : pAh;
  const char* pB = (pass == 1) ? pBl : pBh;
  const uint32_t kOff = (uint32_t)kt * 128;  // kt*64 elems * 2B
  char* la = smembase + (size_t)((g & 1) * 65536) + aLdsOff;
  char* lb = smembase + (size_t)((g & 1) * 65536 + 32768) + bLdsOff;
#pragma unroll
  for (int q = 0; q < 4; ++q) {
    load_lds16(pA + (size_t)(aSrcOff + kOff) + (size_t)q * (8 * KK * 2), la + q * 1024);
    load_lds16(pB + (size_t)(bSrcOff + kOff) + (size_t)q * (8 * KK * 2), lb + q * 1024);
  }
}

__global__ __launch_bounds__(512, 2) void gemm256_kernel(
    const uint16_t* __restrict__ XHi,
    const uint16_t* __restrict__ XLo,
    const uint16_t* __restrict__ BtHi,
    const uint16_t* __restrict__ BtLo,
    const float* __restrict__ bias2,
    float* __restrict__ Out) {
  extern __shared__ __align__(16) char smem[];  // 131072 B

  const int tid = threadIdx.x;
  const int lane = tid & 63;
  const int wq = __builtin_amdgcn_readfirstlane(tid >> 6);  // 0..7
  const int wM = wq >> 2;   // 0..1 -> 128-row half of M
  const int wN = wq & 3;    // 0..3 -> 64-row slab of N
  const int lane31 = lane & 31;
  const int kh = lane >> 5;  // k-half selector

  // XCD-contiguous block swizzle (256 % 8 == 0 -> bijective)
  const int bid = blockIdx.x;
  const int swz = (bid & 7) * 32 + (bid >> 3);
  const int m0 = (swz >> 3) * 256;  // 32 m-tiles
  const int n0 = (swz & 7) * 256;   // 8 n-tiles

  // ---- staging: per-wave own-slab addresses (global src carries the swizzle)
  const uint32_t swzBlk = (uint32_t)(((lane & 7) ^ (lane >> 3)) * 16);
  const uint32_t aSrcOff =
      (uint32_t)(m0 + wM * 128 + wN * 32 + (lane >> 3)) * (KK * 2) + swzBlk;
  const uint32_t bSrcOff =
      (uint32_t)(n0 + wN * 64 + wM * 32 + (lane >> 3)) * (KK * 2) + swzBlk;
  const uint32_t aLdsOff = (uint32_t)(wM * 128 + wN * 32) * 128;
  const uint32_t bLdsOff = (uint32_t)(wN * 64 + wM * 32) * 128;

  // ---- fragment read byte-offsets: row*128 + ((2ks+kh)^(row&7))*16
  uint32_t aRowB[4], bRowB[2], xk[4];
#pragma unroll
  for (int mt = 0; mt < 4; ++mt)
    aRowB[mt] = (uint32_t)(wM * 128 + mt * 32 + lane31) * 128;
#pragma unroll
  for (int nt = 0; nt < 2; ++nt)
    bRowB[nt] = (uint32_t)(wN * 64 + nt * 32 + lane31) * 128;
#pragma unroll
  for (int ks = 0; ks < 4; ++ks)
    xk[ks] = (uint32_t)(((2 * ks + kh) ^ (lane31 & 7)) * 16);

  f32x16 acc[4][2];
#pragma unroll
  for (int mt = 0; mt < 4; ++mt)
#pragma unroll
    for (int nt = 0; nt < 2; ++nt)
#pragma unroll
      for (int r = 0; r < 16; ++r) acc[mt][nt][r] = 0.0f;

  const char* pAh = (const char*)XHi;
  const char* pAl = (const char*)XLo;
  const char* pBh = (const char*)BtHi;
  const char* pBl = (const char*)BtLo;

  // prologue: stage tile 0
  stage_tile(0, smem, pAh, pAl, pBh, pBl, aSrcOff, bSrcOff, aLdsOff, bLdsOff);

  for (int g = 0; g < 192; ++g) {
    if (g + 1 < 192) {
      stage_tile(g + 1, smem, pAh, pAl, pBh, pBl, aSrcOff, bSrcOff, aLdsOff, bLdsOff);
      asm volatile("s_waitcnt vmcnt(8)" ::: "memory");  // tile g arrived; g+1 in flight
    } else {
      asm volatile("s_waitcnt vmcnt(0)" ::: "memory");
    }
    __builtin_amdgcn_s_barrier();        // staging of tile g visible to all waves
    __builtin_amdgcn_sched_barrier(0);   // keep ds_reads below the barrier

    const char* bufA = smem + (size_t)((g & 1) * 65536);
    const char* bufB = bufA + 32768;
#pragma unroll
    for (int ks = 0; ks < 4; ++ks) {
      bf16x8 af[4], bfr[2];
#pragma unroll
      for (int mt = 0; mt < 4; ++mt)
        af[mt] = *(const bf16x8*)(bufA + aRowB[mt] + xk[ks]);
#pragma unroll
      for (int nt = 0; nt < 2; ++nt)
        bfr[nt] = *(const bf16x8*)(bufB + bRowB[nt] + xk[ks]);
      __builtin_amdgcn_s_setprio(1);
#pragma unroll
      for (int mt = 0; mt < 4; ++mt)
#pragma unroll
        for (int nt = 0; nt < 2; ++nt)
          acc[mt][nt] = __builtin_amdgcn_mfma_f32_32x32x16_bf16(
              af[mt], bfr[nt], acc[mt][nt], 0, 0, 0);
      __builtin_amdgcn_s_setprio(0);
    }
    __builtin_amdgcn_s_barrier();  // tile g fully consumed before buf reuse
  }

  // ---- epilogue: out = tanh(acc + bias2) ----
  // C/D layout (verified m74/m101): col = lane&31, row = (r&3) + 8*(r>>2) + 4*kh
#pragma unroll
  for (int nt = 0; nt < 2; ++nt) {
    int col = n0 + wN * 64 + nt * 32 + lane31;
    float b2 = bias2[col];
#pragma unroll
    for (int mt = 0; mt < 4; ++mt) {
#pragma unroll
      for (int r = 0; r < 16; ++r) {
        int rowl = (r & 3) + 8 * (r >> 2) + 4 * kh;
        int grow = m0 + wM * 128 + mt * 32 + rowl;
        float z = acc[mt][nt][r] + b2;
        z = fminf(fmaxf(z, -12.0f), 12.0f);  // tanh saturated well before 12
        float t = __expf(2.0f * z);
        Out[(size_t)grow * NN + col] = (t - 1.0f) / (t + 1.0f);
      }
    }
  }
}

// ---------------------------------------------------------------------------
// Fallback (ws too small): on-the-fly split GEMM, 128x128 tile (verified).
// ---------------------------------------------------------------------------
__global__ __launch_bounds__(256, 4) void unl_gemm_kernel(
    const float* __restrict__ X,
    const uint16_t* __restrict__ BtHi,
    const uint16_t* __restrict__ BtLo,
    const float* __restrict__ bias2,
    float* __restrict__ Out) {
  __shared__ __align__(16) uint8_t smem[32768];
  char* sA = (char*)smem;
  char* sBh = (char*)smem + 16384;
  char* sBl = (char*)smem + 24576;

  const int tid = threadIdx.x;
  const int lane = tid & 63;
  const int wq = __builtin_amdgcn_readfirstlane(tid >> 6);
  const int wM = wq >> 1;
  const int wN = wq & 1;
  const int lane31 = lane & 31;
  const int kh = lane >> 5;

  const int bidx = blockIdx.x;
  const int m0 = (bidx & 63) * 128;
  const int n0 = (bidx >> 6) * 128;

  const int aC = (lane & 7) ^ (lane >> 3);
  const int aVoff = ((lane >> 3) * KK + aC * 4) * 4;
  const char* aBase = (const char*)(X + (size_t)(m0 + wq * 32) * KK) + aVoff;
  const int bC = (lane & 3) ^ ((lane >> 3) & 3);
  const int bVoff = ((lane >> 2) * KK + bC * 8) * 2;
  const char* bBaseH = (const char*)(BtHi + (size_t)(n0 + wq * 32) * KK) + bVoff;
  const char* bBaseL = (const char*)(BtLo + (size_t)(n0 + wq * 32) * KK) + bVoff;

  int aOffB[2][2];
#pragma unroll
  for (int mt = 0; mt < 2; ++mt) {
    int row = wM * 64 + mt * 32 + lane31;
#pragma unroll
    for (int s = 0; s < 2; ++s)
      aOffB[mt][s] = row * 128 + (((4 * s + 2 * kh) ^ (row & 7)) * 16);
  }
  int bOffB[2][2];
#pragma unroll
  for (int nt = 0; nt < 2; ++nt) {
    int row = wN * 64 + nt * 32 + lane31;
#pragma unroll
    for (int s = 0; s < 2; ++s)
      bOffB[nt][s] = row * 64 + (((2 * s + kh) ^ ((row >> 1) & 3)) * 16);
  }

  f32x16 acc[2][2];
#pragma unroll
  for (int mt = 0; mt < 2; ++mt)
#pragma unroll
    for (int nt = 0; nt < 2; ++nt)
#pragma unroll
      for (int r = 0; r < 16; ++r) acc[mt][nt][r] = 0.0f;

  for (int kt = 0; kt < KK; kt += 32) {
    __syncthreads();
#pragma unroll
    for (int q = 0; q < 4; ++q)
      load_lds16(aBase + (size_t)kt * 4 + (size_t)q * (8 * KK * 4),
                 sA + (wq * 4 + q) * 1024);
#pragma unroll
    for (int q = 0; q < 2; ++q) {
      load_lds16(bBaseH + (size_t)kt * 2 + (size_t)q * (16 * KK * 2),
                 sBh + (wq * 2 + q) * 1024);
      load_lds16(bBaseL + (size_t)kt * 2 + (size_t)q * (16 * KK * 2),
                 sBl + (wq * 2 + q) * 1024);
    }
    __syncthreads();

#pragma unroll
    for (int s = 0; s < 2; ++s) {
      bf16x8 ah[2], al[2], bh[2], bl[2];
#pragma unroll
      for (int mt = 0; mt < 2; ++mt) {
        float4 v0 = *(const float4*)(sA + aOffB[mt][s]);
        float4 v1 = *(const float4*)(sA + (aOffB[mt][s] ^ 16));
        FragU uh, ul;
        split4(v0, uh.u[0], uh.u[1], ul.u[0], ul.u[1]);
        split4(v1, uh.u[2], uh.u[3], ul.u[2], ul.u[3]);
        ah[mt] = uh.v;
        al[mt] = ul.v;
      }
#pragma unroll
      for (int nt = 0; nt < 2; ++nt) {
        bh[nt] = *(const bf16x8*)(sBh + bOffB[nt][s]);
        bl[nt] = *(const bf16x8*)(sBl + bOffB[nt][s]);
      }
#pragma unroll
      for (int mt = 0; mt < 2; ++mt) {
#pragma unroll
        for (int nt = 0; nt < 2; ++nt) {
          acc[mt][nt] = __builtin_amdgcn_mfma_f32_32x32x16_bf16(ah[mt], bh[nt], acc[mt][nt], 0, 0, 0);
          acc[mt][nt] = __builtin_amdgcn_mfma_f32_32x32x16_bf16(ah[mt], bl[nt], acc[mt][nt], 0, 0, 0);
          acc[mt][nt] = __builtin_amdgcn_mfma_f32_32x32x16_bf16(al[mt], bh[nt], acc[mt][nt], 0, 0, 0);
        }
      }
    }
  }

#pragma unroll
  for (int nt = 0; nt < 2; ++nt) {
    int col = n0 + wN * 64 + nt * 32 + lane31;
    float b2 = bias2[col];
#pragma unroll
    for (int mt = 0; mt < 2; ++mt) {
#pragma unroll
      for (int r = 0; r < 16; ++r) {
        int rowl = (r & 3) + 8 * (r >> 2) + 4 * kh;
        int grow = m0 + wM * 64 + mt * 32 + rowl;
        float z = acc[mt][nt][r] + b2;
        z = fminf(fmaxf(z, -12.0f), 12.0f);
        float t = __expf(2.0f * z);
        Out[(size_t)grow * NN + col] = (t - 1.0f) / (t + 1.0f);
      }
    }
  }
}

// ---------------------------------------------------------------------------
extern "C" void kernel_launch(void* const* d_in, const int* in_sizes, int n_in,
                              void* d_out, int out_size, void* d_ws, size_t ws_size,
                              hipStream_t stream) {
  const float* x = (const float*)d_in[0];   // (8192, 4096)
  const float* uw = (const float*)d_in[1];  // (9, 4096, 2048)
  const float* cw = (const float*)d_in[2];  // (4096, 2048)
  const float* cb = (const float*)d_in[3];  // (2048,)
  float* out = (float*)d_out;               // (8192, 2048)

  // workspace layout: BtHi (16MB) | BtLo (16MB) | bias2 (8KB) | XHi (64MB) | XLo (64MB)
  uint16_t* btHi = (uint16_t*)d_ws;
  uint16_t* btLo = btHi + (size_t)NN * KK;
  float* bias2 = (float*)(btLo + (size_t)NN * KK);
  uint16_t* xHi = (uint16_t*)(bias2 + NN);
  uint16_t* xLo = xHi + (size_t)MM * KK;

  const size_t need = (size_t)NN * KK * 4   // BtHi+BtLo
                    + (size_t)NN * 4        // bias2
                    + (size_t)MM * KK * 4;  // XHi+XLo

  prep_bt_kernel<<<dim3(KK / 64, NN / 64), 256, 0, stream>>>(cw, btHi, btLo);
  prep_bias_kernel<<<dim3(NN / 256), 256, 0, stream>>>(uw, cb, bias2);

  if (ws_size >= need) {
    prep_x_kernel<<<dim3((MM * KK) / (256 * 8)), 256, 0, stream>>>(x, xHi, xLo);
    static bool attr_set = false;
    if (!attr_set) {
      hipFuncSetAttribute((const void*)gemm256_kernel,
                          hipFuncAttributeMaxDynamicSharedMemorySize, 131072);
      attr_set = true;
    }
    gemm256_kernel<<<dim3((MM / 256) * (NN / 256)), 512, 131072, stream>>>(
        xHi, xLo, btHi, btLo, bias2, out);
  } else {
    unl_gemm_kernel<<<dim3((MM / 128) * (NN / 128)), 256, 0, stream>>>(
        x, btHi, btLo, bias2, out);
  }
}